// Round 1
// baseline (393.090 us; speedup 1.0000x reference)
//
#include <hip/hip_runtime.h>
#include <hip/hip_cooperative_groups.h>
#include <math.h>
#include <limits.h>

namespace cg = cooperative_groups;

#define BB 4
#define SS 2048
#define HH 768
#define MAXSEG 256
#define NUM_POS (BB*(SS/4))   // 2048
#define NEG_BIG -1000000000.0f

typedef _Float16 f16x8 __attribute__((ext_vector_type(8)));
typedef _Float16 f16x4 __attribute__((ext_vector_type(4)));
typedef float    f32x4 __attribute__((ext_vector_type(4)));

// ---------------------------------------------------------------------------
// One cooperative kernel, 6 phases separated by grid.sync().
// Phase work is identical (same FP order) to the verified 6-kernel version;
// only the dispatch boundaries are replaced by grid-wide barriers.
// ---------------------------------------------------------------------------
__global__ __launch_bounds__(256, 2) void k_fused(
    const float* __restrict__ es, const float* __restrict__ W,
    const float* __restrict__ bias, const int* __restrict__ ind,
    const int* __restrict__ clc, float* __restrict__ out,
    char* __restrict__ ws)
{
  // workspace layout (identical to previous version)
  int*   nseg       = (int*)(ws + 0);
  int*   pos_cnt    = (int*)(ws + 256);
  int*   seg_start  = (int*)(ws + 1024);                 // B*(MAXSEG+1)
  int*   seg_id     = (int*)(ws + 8192);                 // B*S
  int*   pos_local  = (int*)(ws + 40960);                // B*S
  int*   allowCnt   = (int*)(ws + 73728);                // B*256
  int*   firstAllow = (int*)(ws + 77824);
  float* lse        = (float*)(ws + 81920);
  int*   amax       = (int*)(ws + 86016);
  _Float16* segsum_h = (_Float16*)(ws + 90112);          // 1024*768*2
  _Float16* Wh       = (_Float16*)(ws + 1662976);        // 768*768*2
  _Float16* Uh       = (_Float16*)(ws + 2842624);
  float*    G        = (float*)(ws + 4415488);           // 1 MB

  cg::grid_group grid = cg::this_grid();
  const int t = threadIdx.x;
  const int lane = t & 63, wid = t >> 6;
  const int nblk = (int)gridDim.x;

  __shared__ int sInd[SS];
  __shared__ int sWave[4];
  __shared__ int sAC[MAXSEG];
  __shared__ int sFA[MAXSEG];
  __shared__ int sBase[BB+1];
  __shared__ float sL0[4], sC0[4], sL1[4], sC1[4];

  // ---- Phase 0: per-batch scans (blocks 0..3 only) ------------------------
  if (blockIdx.x < BB) {
    int b = blockIdx.x;
    for (int i = t; i < SS; i += 256) sInd[i] = ind[b*SS + i];
    sAC[t] = 0; sFA[t] = INT_MAX;
    __syncthreads();

    int i0 = t * 8;
    int f[8], cv[8];
    int lsum = 0;
    #pragma unroll
    for (int u = 0; u < 8; u++) {
      int i = i0 + u;
      f[u] = (i == 0) ? 0 : (sInd[i] != sInd[i-1]);
      cv[u] = clc[b*SS + i];
      lsum += f[u];
    }
    int x = lsum;
    #pragma unroll
    for (int off = 1; off < 64; off <<= 1) {
      int v = __shfl_up(x, off, 64);
      if (lane >= off) x += v;
    }
    if (lane == 63) sWave[wid] = x;
    __syncthreads();
    int base = 0;
    for (int w = 0; w < wid; w++) base += sWave[w];
    int run = base + x - lsum;
    int rid[8];
    #pragma unroll
    for (int u = 0; u < 8; u++) {
      int i = i0 + u;
      run += f[u];
      rid[u] = run;
      seg_id[b*SS + i] = run;
      if (f[u] || i == 0) seg_start[b*(MAXSEG+1) + run] = i;
    }
    if (t == 255) { nseg[b] = run + 1; seg_start[b*(MAXSEG+1) + run + 1] = SS; }

    #pragma unroll
    for (int u = 0; u < 8; u++) {
      if (cv[u] < 0) {
        atomicAdd(&sAC[rid[u]], 1);
        atomicMin(&sFA[rid[u]], i0 + u);
      }
    }
    __syncthreads();
    allowCnt[b*MAXSEG + t]   = sAC[t];
    firstAllow[b*MAXSEG + t] = sFA[t];

    int psum = 0;
    int p[8];
    #pragma unroll
    for (int u = 0; u < 8; u++) { p[u] = (cv[u] > 0) ? 1 : 0; psum += p[u]; }
    x = psum;
    #pragma unroll
    for (int off = 1; off < 64; off <<= 1) {
      int v = __shfl_up(x, off, 64);
      if (lane >= off) x += v;
    }
    __syncthreads();
    if (lane == 63) sWave[wid] = x;
    __syncthreads();
    base = 0;
    for (int w = 0; w < wid; w++) base += sWave[w];
    int rank = base + x - psum;
    #pragma unroll
    for (int u = 0; u < 8; u++) {
      if (p[u]) { pos_local[b*SS + rank] = i0 + u; rank++; }
    }
    if (t == 255) pos_cnt[b] = rank;
  }
  grid.sync();

  // ---- Phase 1: segment sums (f32 acc -> f16) + W f32->f16 cast -----------
  for (int blk = blockIdx.x; blk < BB*MAXSEG + 576; blk += nblk) {
    if (blk >= BB*MAXSEG) {
      int idx = (blk - BB*MAXSEG)*256 + t;     // float4 index; 147456 total
      float4 v = ((const float4*)W)[idx];
      f16x4 h;
      h[0] = (_Float16)v.x; h[1] = (_Float16)v.y;
      h[2] = (_Float16)v.z; h[3] = (_Float16)v.w;
      *(f16x4*)(Wh + (size_t)idx*4) = h;
    } else {
      int b = blk >> 8, s = blk & 255;
      _Float16* o = segsum_h + ((size_t)b*MAXSEG + s)*HH;
      if (s >= nseg[b]) {   // zero-fill missing segments
        o[t] = (_Float16)0.f; o[t+256] = (_Float16)0.f; o[t+512] = (_Float16)0.f;
      } else {
        int st = seg_start[b*(MAXSEG+1) + s];
        int en = seg_start[b*(MAXSEG+1) + s + 1];
        const float* bp = es + (size_t)b*SS*HH;
        float a0 = 0.f, a1 = 0.f, a2 = 0.f;
        for (int i = st; i < en; i++) {
          const float* r = bp + (size_t)i*HH;
          a0 += r[t]; a1 += r[t+256]; a2 += r[t+512];
        }
        o[t] = (_Float16)a0; o[t+256] = (_Float16)a1; o[t+512] = (_Float16)a2;
      }
    }
  }
  grid.sync();

  // ---- Phase 2: U = tanh(segsum @ Wh^T + bias), wave = 32x32 tile ---------
  {
    int gw = blockIdx.x*4 + wid;
    for (int tile = gw; tile < 768; tile += nblk*4) {
      int tm = tile / 24, tn = tile % 24;
      int rb = tm*32, cb = tn*32;
      int m0 = lane & 15, quad = lane >> 4;
      const _Float16* A0 = segsum_h + (size_t)(rb + m0)*HH + quad*8;
      const _Float16* A1 = A0 + (size_t)16*HH;
      const _Float16* B0 = Wh + (size_t)(cb + m0)*HH + quad*8;
      const _Float16* B1 = B0 + (size_t)16*HH;
      f32x4 acc00 = {0.f,0.f,0.f,0.f}, acc01 = {0.f,0.f,0.f,0.f};
      f32x4 acc10 = {0.f,0.f,0.f,0.f}, acc11 = {0.f,0.f,0.f,0.f};
      #pragma unroll 4
      for (int k0 = 0; k0 < HH; k0 += 32) {
        f16x8 a0 = *(const f16x8*)(A0 + k0);
        f16x8 a1 = *(const f16x8*)(A1 + k0);
        f16x8 b0 = *(const f16x8*)(B0 + k0);
        f16x8 b1 = *(const f16x8*)(B1 + k0);
        acc00 = __builtin_amdgcn_mfma_f32_16x16x32_f16(a0, b0, acc00, 0, 0, 0);
        acc01 = __builtin_amdgcn_mfma_f32_16x16x32_f16(a0, b1, acc01, 0, 0, 0);
        acc10 = __builtin_amdgcn_mfma_f32_16x16x32_f16(a1, b0, acc10, 0, 0, 0);
        acc11 = __builtin_amdgcn_mfma_f32_16x16x32_f16(a1, b1, acc11, 0, 0, 0);
      }
      float bc0 = bias[cb + m0], bc1 = bias[cb + 16 + m0];
      int r0 = rb + quad*4;
      #pragma unroll
      for (int i = 0; i < 4; i++) {
        Uh[(size_t)(r0+i)*HH    + cb + m0]      = (_Float16)tanhf(acc00[i] + bc0);
        Uh[(size_t)(r0+i)*HH    + cb + 16 + m0] = (_Float16)tanhf(acc01[i] + bc1);
        Uh[(size_t)(r0+16+i)*HH + cb + m0]      = (_Float16)tanhf(acc10[i] + bc0);
        Uh[(size_t)(r0+16+i)*HH + cb + 16 + m0] = (_Float16)tanhf(acc11[i] + bc1);
      }
    }
  }
  grid.sync();

  // ---- Phase 3: Gram G[b] = U[b] U[b]^T, wave = 16x16 tile ----------------
  {
    int gw = blockIdx.x*4 + wid;
    for (int tile = gw; tile < BB*256; tile += nblk*4) {
      int b = tile >> 8, rem = tile & 255;
      int rb = (rem >> 4)*16, cb = (rem & 15)*16;
      int m0 = lane & 15, quad = lane >> 4;
      const _Float16* Ub = Uh + (size_t)b*MAXSEG*HH;
      const _Float16* A0 = Ub + (size_t)(rb + m0)*HH + quad*8;
      const _Float16* B0 = Ub + (size_t)(cb + m0)*HH + quad*8;
      f32x4 acc = {0.f,0.f,0.f,0.f};
      #pragma unroll 4
      for (int k0 = 0; k0 < HH; k0 += 32) {
        f16x8 a  = *(const f16x8*)(A0 + k0);
        f16x8 bb = *(const f16x8*)(B0 + k0);
        acc = __builtin_amdgcn_mfma_f32_16x16x32_f16(a, bb, acc, 0, 0, 0);
      }
      float* Gb = G + (size_t)b*MAXSEG*MAXSEG;
      int r0 = rb + quad*4;
      #pragma unroll
      for (int i = 0; i < 4; i++)
        Gb[(size_t)(r0+i)*MAXSEG + cb + m0] = acc[i];
    }
  }
  grid.sync();

  // ---- Phase 4: per (b,seg) row: masked logsumexp + first-occ argmax ------
  {
    int gw = blockIdx.x*4 + wid;
    for (int row = gw; row < BB*MAXSEG; row += nblk*4) {
      int b = row >> 8, si = row & 255;
      if (si < nseg[b]) {
        const float* g = G + ((size_t)b*MAXSEG + si)*MAXSEG;
        const int* ac = allowCnt + b*MAXSEG;
        const int* fa = firstAllow + b*MAXSEG;
        float gv[4]; int av[4], fv[4];
        #pragma unroll
        for (int q = 0; q < 4; q++) {
          int s = lane + 64*q;
          gv[q] = g[s]; av[q] = ac[s]; fv[q] = fa[s];
        }
        float m = -INFINITY;
        #pragma unroll
        for (int q = 0; q < 4; q++) if (av[q] > 0) m = fmaxf(m, gv[q]);
        #pragma unroll
        for (int off = 32; off > 0; off >>= 1) m = fmaxf(m, __shfl_xor(m, off, 64));
        float s = 0.f;
        #pragma unroll
        for (int q = 0; q < 4; q++) if (av[q] > 0) s += (float)av[q] * expf(gv[q] - m);
        #pragma unroll
        for (int off = 32; off > 0; off >>= 1) s += __shfl_xor(s, off, 64);
        float bv = -INFINITY; int bi = INT_MAX;
        #pragma unroll
        for (int q = 0; q < 4; q++) {
          if (av[q] > 0 && (gv[q] > bv || (gv[q] == bv && fv[q] < bi))) { bv = gv[q]; bi = fv[q]; }
        }
        #pragma unroll
        for (int off = 32; off > 0; off >>= 1) {
          float ov = __shfl_xor(bv, off, 64);
          int   oi = __shfl_xor(bi, off, 64);
          if (ov > bv || (ov == bv && oi < bi)) { bv = ov; bi = oi; }
        }
        if (lane == 0) {
          lse[row]  = m + logf(s);
          amax[row] = bi;
        }
      }
    }
  }
  grid.sync();

  // ---- Phase 5: finalize (block 0 only, same reduction order as before) ---
  if (blockIdx.x == 0) {
    if (t == 0) {
      int acc = 0; sBase[0] = 0;
      for (int b = 0; b < BB; b++) { acc += pos_cnt[b]; sBase[b+1] = acc; }
    }
    __syncthreads();
    int total = sBase[BB];
    if (total > NUM_POS) total = NUM_POS;
    float l0 = 0.f, c0 = 0.f, l1 = 0.f, c1 = 0.f;
    for (int r = t; r < total; r += 256) {
      int b = 0;
      while (b < BB-1 && r >= sBase[b+1]) b++;
      int k = r - sBase[b];
      int i  = pos_local[b*SS + k];
      int si = seg_id[b*SS + i];
      int L  = clc[b*SS + i];
      int sL = seg_id[b*SS + L];
      float vL = G[((size_t)b*MAXSEG + si)*MAXSEG + sL] + (clc[b*SS + L] < 0 ? 0.0f : NEG_BIG);
      float loss = lse[b*MAXSEG + si] - vL;
      float corr = (amax[b*MAXSEG + si] == L) ? 1.0f : 0.0f;
      if (r & 1) { l1 += loss; c1 += corr; } else { l0 += loss; c0 += corr; }
    }
    #pragma unroll
    for (int off = 32; off > 0; off >>= 1) {
      l0 += __shfl_down(l0, off, 64);
      c0 += __shfl_down(c0, off, 64);
      l1 += __shfl_down(l1, off, 64);
      c1 += __shfl_down(c1, off, 64);
    }
    if (lane == 0) { sL0[wid] = l0; sC0[wid] = c0; sL1[wid] = l1; sC1[wid] = c1; }
    __syncthreads();
    if (t == 0) {
      float L0 = sL0[0]+sL0[1]+sL0[2]+sL0[3];
      float C0 = sC0[0]+sC0[1]+sC0[2]+sC0[3];
      float L1 = sL1[0]+sL1[1]+sL1[2]+sL1[3];
      float C1 = sC1[0]+sC1[1]+sC1[2]+sC1[3];
      float n = (float)(NUM_POS/2);   // 1024
      out[0] = L0 / n;
      out[1] = C0;
      out[2] = n + 1e-6f;
      out[3] = L1 / n;
      out[4] = C1;
      out[5] = n + 1e-6f;
    }
  }
}

// ---------------------------------------------------------------------------
extern "C" void kernel_launch(void* const* d_in, const int* in_sizes, int n_in,
                              void* d_out, int out_size, void* d_ws, size_t ws_size,
                              hipStream_t stream)
{
  const float* es   = (const float*)d_in[0];
  const float* W    = (const float*)d_in[1];
  const float* bias = (const float*)d_in[2];
  const int*   ind  = (const int*)d_in[3];
  const int*   clc  = (const int*)d_in[4];
  float* out = (float*)d_out;
  char*  wsp = (char*)d_ws;

  // size grid to guaranteed co-residency (cooperative launch requirement)
  static int grid = 0;
  if (grid == 0) {
    int nb = 0;
    hipOccupancyMaxActiveBlocksPerMultiprocessor(&nb, k_fused, 256, 0);
    if (nb < 1) nb = 1;
    grid = nb * 256;              // 256 CUs on MI355X
    if (grid > 512) grid = 512;   // 2 blocks/CU is all we need
    if (grid < 4) grid = 4;       // phase 0 needs 4 blocks
  }

  void* args[] = {(void*)&es, (void*)&W, (void*)&bias, (void*)&ind,
                  (void*)&clc, (void*)&out, (void*)&wsp};
  hipLaunchCooperativeKernel(k_fused, dim3(grid), dim3(256), args, 0, stream);
}

// Round 2
// 133.781 us; speedup vs baseline: 2.9383x; 2.9383x over previous
//
#include <hip/hip_runtime.h>
#include <math.h>
#include <limits.h>

#define BB 4
#define SS 2048
#define HH 768
#define MAXSEG 256
#define NUM_POS (BB*(SS/4))   // 2048
#define NEG_BIG -1000000000.0f

typedef _Float16 f16x8 __attribute__((ext_vector_type(8)));
typedef _Float16 f16x4 __attribute__((ext_vector_type(4)));
typedef float    f32x4 __attribute__((ext_vector_type(4)));

// ---------------------------------------------------------------------------
// Kernel A: blocks 0..3: per-batch scans. Blocks 4..579: W f32->f16 cast
// (independent work folded into the same dispatch).
// ---------------------------------------------------------------------------
__global__ __launch_bounds__(256) void k_scanW(
    const int* __restrict__ ind, const int* __restrict__ clc,
    const float* __restrict__ W, _Float16* __restrict__ Wh,
    int* __restrict__ seg_id, int* __restrict__ seg_start,
    int* __restrict__ nseg, int* __restrict__ pos_local, int* __restrict__ pos_cnt,
    int* __restrict__ allowCnt, int* __restrict__ firstAllow)
{
  int t = threadIdx.x;
  if (blockIdx.x >= BB) {
    int idx = (blockIdx.x - BB)*256 + t;     // float4 index; 147456 total
    float4 v = ((const float4*)W)[idx];
    f16x4 h;
    h[0] = (_Float16)v.x; h[1] = (_Float16)v.y;
    h[2] = (_Float16)v.z; h[3] = (_Float16)v.w;
    *(f16x4*)(Wh + (size_t)idx*4) = h;
    return;
  }
  int b = blockIdx.x;
  int lane = t & 63, wid = t >> 6;
  __shared__ int sInd[SS];
  __shared__ int sWave[4];
  __shared__ int sAC[MAXSEG];
  __shared__ int sFA[MAXSEG];
  for (int i = t; i < SS; i += 256) sInd[i] = ind[b*SS + i];
  sAC[t] = 0; sFA[t] = INT_MAX;
  __syncthreads();

  int i0 = t * 8;
  int f[8], cv[8];
  int lsum = 0;
  #pragma unroll
  for (int u = 0; u < 8; u++) {
    int i = i0 + u;
    f[u] = (i == 0) ? 0 : (sInd[i] != sInd[i-1]);
    cv[u] = clc[b*SS + i];
    lsum += f[u];
  }
  int x = lsum;
  #pragma unroll
  for (int off = 1; off < 64; off <<= 1) {
    int v = __shfl_up(x, off, 64);
    if (lane >= off) x += v;
  }
  if (lane == 63) sWave[wid] = x;
  __syncthreads();
  int base = 0;
  for (int w = 0; w < wid; w++) base += sWave[w];
  int run = base + x - lsum;
  int rid[8];
  #pragma unroll
  for (int u = 0; u < 8; u++) {
    int i = i0 + u;
    run += f[u];
    rid[u] = run;
    seg_id[b*SS + i] = run;
    if (f[u] || i == 0) seg_start[b*(MAXSEG+1) + run] = i;
  }
  if (t == 255) { nseg[b] = run + 1; seg_start[b*(MAXSEG+1) + run + 1] = SS; }

  #pragma unroll
  for (int u = 0; u < 8; u++) {
    if (cv[u] < 0) {
      atomicAdd(&sAC[rid[u]], 1);
      atomicMin(&sFA[rid[u]], i0 + u);
    }
  }
  __syncthreads();
  allowCnt[b*MAXSEG + t]   = sAC[t];
  firstAllow[b*MAXSEG + t] = sFA[t];

  int psum = 0;
  int p[8];
  #pragma unroll
  for (int u = 0; u < 8; u++) { p[u] = (cv[u] > 0) ? 1 : 0; psum += p[u]; }
  x = psum;
  #pragma unroll
  for (int off = 1; off < 64; off <<= 1) {
    int v = __shfl_up(x, off, 64);
    if (lane >= off) x += v;
  }
  __syncthreads();
  if (lane == 63) sWave[wid] = x;
  __syncthreads();
  base = 0;
  for (int w = 0; w < wid; w++) base += sWave[w];
  int rank = base + x - psum;
  #pragma unroll
  for (int u = 0; u < 8; u++) {
    if (p[u]) { pos_local[b*SS + rank] = i0 + u; rank++; }
  }
  if (t == 255) pos_cnt[b] = rank;
}

// ---------------------------------------------------------------------------
// Kernel B: segment sums (f32 accumulate -> f16 out). 4-row manual unroll:
// 12 independent loads in flight per iteration cuts the serial-latency tail
// of the longest segment ~4x.
// ---------------------------------------------------------------------------
__global__ __launch_bounds__(256) void k_segsum(
    const float* __restrict__ es,
    const int* __restrict__ seg_start, const int* __restrict__ nseg,
    _Float16* __restrict__ segsum_h)
{
  int blk = blockIdx.x, t = threadIdx.x;
  int b = blk >> 8, s = blk & 255;
  _Float16* o = segsum_h + ((size_t)b*MAXSEG + s)*HH;
  if (s >= nseg[b]) {   // zero-fill missing segments (keep downstream NaN-free)
    o[t] = (_Float16)0.f; o[t+256] = (_Float16)0.f; o[t+512] = (_Float16)0.f;
    return;
  }
  int st = seg_start[b*(MAXSEG+1) + s];
  int en = seg_start[b*(MAXSEG+1) + s + 1];
  const float* base = es + (size_t)b*SS*HH;
  float a0 = 0.f, a1 = 0.f, a2 = 0.f;
  float b0 = 0.f, b1 = 0.f, b2 = 0.f;
  float c0 = 0.f, c1 = 0.f, c2 = 0.f;
  float d0 = 0.f, d1 = 0.f, d2 = 0.f;
  int i = st;
  for (; i + 4 <= en; i += 4) {
    const float* r0 = base + (size_t)i*HH;
    const float* r1 = r0 + HH;
    const float* r2 = r1 + HH;
    const float* r3 = r2 + HH;
    a0 += r0[t]; a1 += r0[t+256]; a2 += r0[t+512];
    b0 += r1[t]; b1 += r1[t+256]; b2 += r1[t+512];
    c0 += r2[t]; c1 += r2[t+256]; c2 += r2[t+512];
    d0 += r3[t]; d1 += r3[t+256]; d2 += r3[t+512];
  }
  for (; i < en; i++) {
    const float* r = base + (size_t)i*HH;
    a0 += r[t]; a1 += r[t+256]; a2 += r[t+512];
  }
  o[t]     = (_Float16)((a0 + b0) + (c0 + d0));
  o[t+256] = (_Float16)((a1 + b1) + (c1 + d1));
  o[t+512] = (_Float16)((a2 + b2) + (c2 + d2));
}

// ---------------------------------------------------------------------------
// Kernel C: U = tanh(segsum @ W^T + bias), f16 MFMA, direct-global fragments.
// Wave = independent 32x32 tile (2x2 of 16x16x32). 768 tiles -> 192 blocks.
// ---------------------------------------------------------------------------
__global__ __launch_bounds__(256) void k_gemmU(
    const _Float16* __restrict__ Ah, const _Float16* __restrict__ Wh,
    const float* __restrict__ bias, _Float16* __restrict__ Uh)
{
  int tid = threadIdx.x;
  int w = tid >> 6, lane = tid & 63;
  int tile = blockIdx.x*4 + w;          // 0..767 over 32 x 24 tiles
  int tm = tile / 24, tn = tile % 24;
  int rb = tm*32, cb = tn*32;
  int m0 = lane & 15, quad = lane >> 4;
  const _Float16* A0 = Ah + (size_t)(rb + m0)*HH + quad*8;
  const _Float16* A1 = A0 + (size_t)16*HH;
  const _Float16* B0 = Wh + (size_t)(cb + m0)*HH + quad*8;
  const _Float16* B1 = B0 + (size_t)16*HH;
  f32x4 acc00 = {0.f,0.f,0.f,0.f}, acc01 = {0.f,0.f,0.f,0.f};
  f32x4 acc10 = {0.f,0.f,0.f,0.f}, acc11 = {0.f,0.f,0.f,0.f};
  #pragma unroll 4
  for (int k0 = 0; k0 < HH; k0 += 32) {
    f16x8 a0 = *(const f16x8*)(A0 + k0);
    f16x8 a1 = *(const f16x8*)(A1 + k0);
    f16x8 b0 = *(const f16x8*)(B0 + k0);
    f16x8 b1 = *(const f16x8*)(B1 + k0);
    acc00 = __builtin_amdgcn_mfma_f32_16x16x32_f16(a0, b0, acc00, 0, 0, 0);
    acc01 = __builtin_amdgcn_mfma_f32_16x16x32_f16(a0, b1, acc01, 0, 0, 0);
    acc10 = __builtin_amdgcn_mfma_f32_16x16x32_f16(a1, b0, acc10, 0, 0, 0);
    acc11 = __builtin_amdgcn_mfma_f32_16x16x32_f16(a1, b1, acc11, 0, 0, 0);
  }
  float bc0 = bias[cb + m0], bc1 = bias[cb + 16 + m0];
  int r0 = rb + quad*4;
  #pragma unroll
  for (int i = 0; i < 4; i++) {
    Uh[(size_t)(r0+i)*HH    + cb + m0]      = (_Float16)tanhf(acc00[i] + bc0);
    Uh[(size_t)(r0+i)*HH    + cb + 16 + m0] = (_Float16)tanhf(acc01[i] + bc1);
    Uh[(size_t)(r0+16+i)*HH + cb + m0]      = (_Float16)tanhf(acc10[i] + bc0);
    Uh[(size_t)(r0+16+i)*HH + cb + 16 + m0] = (_Float16)tanhf(acc11[i] + bc1);
  }
}

// ---------------------------------------------------------------------------
// Kernel D: fused Gram panel + row-LSE. Block = (b, 16-row panel).
// 4 waves x 4 col-tiles each (A fragment reused across col-tiles).
// G panel kept in LDS; after syncthreads each wave does 4 rows of
// masked logsumexp + first-occurrence argmax (identical reduction order
// to the previous separate kernel).
// ---------------------------------------------------------------------------
__global__ __launch_bounds__(256) void k_gramlse(
    const _Float16* __restrict__ Uh, const int* __restrict__ allowCnt,
    const int* __restrict__ firstAllow, const int* __restrict__ nseg,
    float* __restrict__ G, float* __restrict__ lse, int* __restrict__ amax)
{
  __shared__ float sG[16][257];          // +1 pad: quad rows hit distinct banks
  int t = threadIdx.x;
  int lane = t & 63, w = t >> 6;
  int blk = blockIdx.x;                  // 0..63
  int b = blk >> 4;
  int rb = (blk & 15) * 16;
  int m0 = lane & 15, quad = lane >> 4;
  const _Float16* Ub = Uh + (size_t)b*MAXSEG*HH;
  const _Float16* A0 = Ub + (size_t)(rb + m0)*HH + quad*8;
  int cb0 = w * 64;                      // this wave's 4 col-tiles
  const _Float16* B0 = Ub + (size_t)(cb0      + m0)*HH + quad*8;
  const _Float16* B1 = Ub + (size_t)(cb0 + 16 + m0)*HH + quad*8;
  const _Float16* B2 = Ub + (size_t)(cb0 + 32 + m0)*HH + quad*8;
  const _Float16* B3 = Ub + (size_t)(cb0 + 48 + m0)*HH + quad*8;
  f32x4 acc0 = {0.f,0.f,0.f,0.f}, acc1 = {0.f,0.f,0.f,0.f};
  f32x4 acc2 = {0.f,0.f,0.f,0.f}, acc3 = {0.f,0.f,0.f,0.f};
  #pragma unroll 4
  for (int k0 = 0; k0 < HH; k0 += 32) {
    f16x8 a  = *(const f16x8*)(A0 + k0);
    f16x8 q0 = *(const f16x8*)(B0 + k0);
    f16x8 q1 = *(const f16x8*)(B1 + k0);
    f16x8 q2 = *(const f16x8*)(B2 + k0);
    f16x8 q3 = *(const f16x8*)(B3 + k0);
    acc0 = __builtin_amdgcn_mfma_f32_16x16x32_f16(a, q0, acc0, 0, 0, 0);
    acc1 = __builtin_amdgcn_mfma_f32_16x16x32_f16(a, q1, acc1, 0, 0, 0);
    acc2 = __builtin_amdgcn_mfma_f32_16x16x32_f16(a, q2, acc2, 0, 0, 0);
    acc3 = __builtin_amdgcn_mfma_f32_16x16x32_f16(a, q3, acc3, 0, 0, 0);
  }
  float* Gb = G + (size_t)b*MAXSEG*MAXSEG;
  int r0 = quad*4;
  #pragma unroll
  for (int i = 0; i < 4; i++) {
    int rl = r0 + i;
    sG[rl][cb0      + m0] = acc0[i];
    sG[rl][cb0 + 16 + m0] = acc1[i];
    sG[rl][cb0 + 32 + m0] = acc2[i];
    sG[rl][cb0 + 48 + m0] = acc3[i];
    float* gr = Gb + (size_t)(rb + rl)*MAXSEG;
    gr[cb0      + m0] = acc0[i];
    gr[cb0 + 16 + m0] = acc1[i];
    gr[cb0 + 32 + m0] = acc2[i];
    gr[cb0 + 48 + m0] = acc3[i];
  }
  __syncthreads();

  // ---- row LSE + argmax from LDS; wave w handles rows rb+w*4 .. rb+w*4+3 --
  const int* ac = allowCnt + b*MAXSEG;
  const int* fa = firstAllow + b*MAXSEG;
  int ns = nseg[b];
  #pragma unroll
  for (int j = 0; j < 4; j++) {
    int rl = w*4 + j;
    int si = rb + rl;
    if (si >= ns) continue;
    float gv[4]; int av[4], fv[4];
    #pragma unroll
    for (int q = 0; q < 4; q++) {
      int s = lane + 64*q;
      gv[q] = sG[rl][s]; av[q] = ac[s]; fv[q] = fa[s];
    }
    float m = -INFINITY;
    #pragma unroll
    for (int q = 0; q < 4; q++) if (av[q] > 0) m = fmaxf(m, gv[q]);
    #pragma unroll
    for (int off = 32; off > 0; off >>= 1) m = fmaxf(m, __shfl_xor(m, off, 64));
    float s = 0.f;
    #pragma unroll
    for (int q = 0; q < 4; q++) if (av[q] > 0) s += (float)av[q] * expf(gv[q] - m);
    #pragma unroll
    for (int off = 32; off > 0; off >>= 1) s += __shfl_xor(s, off, 64);
    float bv = -INFINITY; int bi = INT_MAX;
    #pragma unroll
    for (int q = 0; q < 4; q++) {
      if (av[q] > 0 && (gv[q] > bv || (gv[q] == bv && fv[q] < bi))) { bv = gv[q]; bi = fv[q]; }
    }
    #pragma unroll
    for (int off = 32; off > 0; off >>= 1) {
      float ov = __shfl_xor(bv, off, 64);
      int   oi = __shfl_xor(bi, off, 64);
      if (ov > bv || (ov == bv && oi < bi)) { bv = ov; bi = oi; }
    }
    if (lane == 0) {
      lse[b*MAXSEG + si]  = m + logf(s);
      amax[b*MAXSEG + si] = bi;
    }
  }
}

// ---------------------------------------------------------------------------
// Kernel E: single block — all positives, LDS reduction, finalize 6 scalars.
// ---------------------------------------------------------------------------
__global__ __launch_bounds__(256) void k_posfinal(
    const float* __restrict__ G, const int* __restrict__ seg_id,
    const int* __restrict__ clc, const int* __restrict__ pos_local,
    const int* __restrict__ pos_cnt, const float* __restrict__ lse,
    const int* __restrict__ amax, float* __restrict__ out)
{
  __shared__ int sBase[BB+1];
  __shared__ float sL0[4], sC0[4], sL1[4], sC1[4];
  int t = threadIdx.x;
  if (t == 0) {
    int acc = 0; sBase[0] = 0;
    for (int b = 0; b < BB; b++) { acc += pos_cnt[b]; sBase[b+1] = acc; }
  }
  __syncthreads();
  int total = sBase[BB];
  if (total > NUM_POS) total = NUM_POS;
  float l0 = 0.f, c0 = 0.f, l1 = 0.f, c1 = 0.f;
  for (int r = t; r < total; r += 256) {
    int b = 0;
    while (b < BB-1 && r >= sBase[b+1]) b++;
    int k = r - sBase[b];
    int i  = pos_local[b*SS + k];
    int si = seg_id[b*SS + i];
    int L  = clc[b*SS + i];
    int sL = seg_id[b*SS + L];
    float vL = G[((size_t)b*MAXSEG + si)*MAXSEG + sL] + (clc[b*SS + L] < 0 ? 0.0f : NEG_BIG);
    float loss = lse[b*MAXSEG + si] - vL;
    float corr = (amax[b*MAXSEG + si] == L) ? 1.0f : 0.0f;
    if (r & 1) { l1 += loss; c1 += corr; } else { l0 += loss; c0 += corr; }
  }
  int lane = t & 63, wid = t >> 6;
  #pragma unroll
  for (int off = 32; off > 0; off >>= 1) {
    l0 += __shfl_down(l0, off, 64);
    c0 += __shfl_down(c0, off, 64);
    l1 += __shfl_down(l1, off, 64);
    c1 += __shfl_down(c1, off, 64);
  }
  if (lane == 0) { sL0[wid] = l0; sC0[wid] = c0; sL1[wid] = l1; sC1[wid] = c1; }
  __syncthreads();
  if (t == 0) {
    float L0 = sL0[0]+sL0[1]+sL0[2]+sL0[3];
    float C0 = sC0[0]+sC0[1]+sC0[2]+sC0[3];
    float L1 = sL1[0]+sL1[1]+sL1[2]+sL1[3];
    float C1 = sC1[0]+sC1[1]+sC1[2]+sC1[3];
    float n = (float)(NUM_POS/2);   // 1024
    out[0] = L0 / n;
    out[1] = C0;
    out[2] = n + 1e-6f;
    out[3] = L1 / n;
    out[4] = C1;
    out[5] = n + 1e-6f;
  }
}

// ---------------------------------------------------------------------------
extern "C" void kernel_launch(void* const* d_in, const int* in_sizes, int n_in,
                              void* d_out, int out_size, void* d_ws, size_t ws_size,
                              hipStream_t stream)
{
  const float* es   = (const float*)d_in[0];
  const float* W    = (const float*)d_in[1];
  const float* bias = (const float*)d_in[2];
  const int*   ind  = (const int*)d_in[3];
  const int*   clc  = (const int*)d_in[4];
  float* out = (float*)d_out;

  char* ws = (char*)d_ws;
  int*   nseg       = (int*)(ws + 0);
  int*   pos_cnt    = (int*)(ws + 256);
  int*   seg_start  = (int*)(ws + 1024);                 // B*(MAXSEG+1)
  int*   seg_id     = (int*)(ws + 8192);                 // B*S
  int*   pos_local  = (int*)(ws + 40960);                // B*S
  int*   allowCnt   = (int*)(ws + 73728);                // B*256
  int*   firstAllow = (int*)(ws + 77824);
  float* lse        = (float*)(ws + 81920);
  int*   amax       = (int*)(ws + 86016);
  _Float16* segsum_h = (_Float16*)(ws + 90112);          // 1024*768*2 = 1.5 MB
  _Float16* Wh       = (_Float16*)(ws + 1662976);        // 768*768*2 = 1.125 MB
  _Float16* Uh       = (_Float16*)(ws + 2842624);        // 1.5 MB
  float*    G        = (float*)(ws + 4415488);           // 1 MB

  k_scanW<<<BB + 576, 256, 0, stream>>>(ind, clc, W, Wh, seg_id, seg_start,
                                        nseg, pos_local, pos_cnt, allowCnt, firstAllow);
  k_segsum<<<BB*MAXSEG, 256, 0, stream>>>(es, seg_start, nseg, segsum_h);
  k_gemmU<<<192, 256, 0, stream>>>(segsum_h, Wh, bias, Uh);
  k_gramlse<<<BB*16, 256, 0, stream>>>(Uh, allowCnt, firstAllow, nseg, G, lse, amax);
  k_posfinal<<<1, 256, 0, stream>>>(G, seg_id, clc, pos_local, pos_cnt, lse, amax, out);
}

// Round 3
// 133.488 us; speedup vs baseline: 2.9448x; 1.0022x over previous
//
#include <hip/hip_runtime.h>
#include <math.h>
#include <limits.h>

#define BB 4
#define SS 2048
#define HH 768
#define MAXSEG 256
#define NUM_POS (BB*(SS/4))   // 2048
#define NEG_BIG -1000000000.0f

typedef _Float16 f16x8 __attribute__((ext_vector_type(8)));
typedef _Float16 f16x4 __attribute__((ext_vector_type(4)));
typedef float    f32x4 __attribute__((ext_vector_type(4)));

// ---------------------------------------------------------------------------
// D1: one dispatch, three block roles (no cross-block data flow):
//   blocks [0, 1024): segment sums — each block recomputes its batch's scan
//                     from ind in LDS (redundant, removes scan->segsum dep)
//   blocks [1024, 1028): per-batch scan outputs (seg_id/pos/allow for D3/D4)
//   blocks [1028, 1604): W f32->f16 cast
// ---------------------------------------------------------------------------
__global__ __launch_bounds__(256) void k_stage1(
    const float* __restrict__ es, const float* __restrict__ W,
    const int* __restrict__ ind, const int* __restrict__ clc,
    _Float16* __restrict__ Wh, _Float16* __restrict__ segsum_h,
    int* __restrict__ seg_id, int* __restrict__ nseg,
    int* __restrict__ pos_local, int* __restrict__ pos_cnt,
    int* __restrict__ allowCnt, int* __restrict__ firstAllow)
{
  int t = threadIdx.x;
  int blk = blockIdx.x;

  if (blk >= BB*MAXSEG + BB) {               // ---- W cast ----
    int idx = (blk - (BB*MAXSEG + BB))*256 + t;   // float4 index; 147456 total
    float4 v = ((const float4*)W)[idx];
    f16x4 h;
    h[0] = (_Float16)v.x; h[1] = (_Float16)v.y;
    h[2] = (_Float16)v.z; h[3] = (_Float16)v.w;
    *(f16x4*)(Wh + (size_t)idx*4) = h;
    return;
  }

  int lane = t & 63, wid = t >> 6;
  __shared__ int sInd[SS];
  __shared__ int sWave[4];
  __shared__ int sStart[MAXSEG+1];
  __shared__ int sNs;
  __shared__ int sAC[MAXSEG];
  __shared__ int sFA[MAXSEG];

  if (blk < BB*MAXSEG) {                     // ---- segment sum ----
    int b = blk >> 8, s = blk & 255;
    for (int i = t; i < SS; i += 256) sInd[i] = ind[b*SS + i];
    __syncthreads();

    // redundant per-block scan: flags -> prefix -> run-start table in LDS
    int i0 = t * 8;
    int f[8]; int lsum = 0;
    #pragma unroll
    for (int u = 0; u < 8; u++) {
      int i = i0 + u;
      f[u] = (i == 0) ? 0 : (sInd[i] != sInd[i-1]);
      lsum += f[u];
    }
    int x = lsum;
    #pragma unroll
    for (int off = 1; off < 64; off <<= 1) {
      int v = __shfl_up(x, off, 64);
      if (lane >= off) x += v;
    }
    if (lane == 63) sWave[wid] = x;
    __syncthreads();
    int base = 0;
    for (int w2 = 0; w2 < wid; w2++) base += sWave[w2];
    int run = base + x - lsum;
    #pragma unroll
    for (int u = 0; u < 8; u++) {
      int i = i0 + u;
      run += f[u];
      if (f[u] || i == 0) sStart[run] = i;
    }
    if (t == 255) { sStart[run + 1] = SS; sNs = run + 1; }
    __syncthreads();

    _Float16* o = segsum_h + ((size_t)b*MAXSEG + s)*HH;
    if (s >= sNs) {   // zero-fill missing segments (keep downstream NaN-free)
      o[t] = (_Float16)0.f; o[t+256] = (_Float16)0.f; o[t+512] = (_Float16)0.f;
      return;
    }
    int st = sStart[s];
    int en = sStart[s + 1];
    const float* bp = es + (size_t)b*SS*HH;
    float a0 = 0.f, a1 = 0.f, a2 = 0.f;
    float b0 = 0.f, b1 = 0.f, b2 = 0.f;
    float c0 = 0.f, c1 = 0.f, c2 = 0.f;
    float d0 = 0.f, d1 = 0.f, d2 = 0.f;
    int i = st;
    for (; i + 4 <= en; i += 4) {
      const float* r0 = bp + (size_t)i*HH;
      const float* r1 = r0 + HH;
      const float* r2 = r1 + HH;
      const float* r3 = r2 + HH;
      a0 += r0[t]; a1 += r0[t+256]; a2 += r0[t+512];
      b0 += r1[t]; b1 += r1[t+256]; b2 += r1[t+512];
      c0 += r2[t]; c1 += r2[t+256]; c2 += r2[t+512];
      d0 += r3[t]; d1 += r3[t+256]; d2 += r3[t+512];
    }
    for (; i < en; i++) {
      const float* r = bp + (size_t)i*HH;
      a0 += r[t]; a1 += r[t+256]; a2 += r[t+512];
    }
    o[t]     = (_Float16)((a0 + b0) + (c0 + d0));
    o[t+256] = (_Float16)((a1 + b1) + (c1 + d1));
    o[t+512] = (_Float16)((a2 + b2) + (c2 + d2));
    return;
  }

  // ---- per-batch scan outputs (4 blocks) ----
  {
    int b = blk - BB*MAXSEG;
    for (int i = t; i < SS; i += 256) sInd[i] = ind[b*SS + i];
    sAC[t] = 0; sFA[t] = INT_MAX;
    __syncthreads();

    int i0 = t * 8;
    int f[8], cv[8];
    int lsum = 0;
    #pragma unroll
    for (int u = 0; u < 8; u++) {
      int i = i0 + u;
      f[u] = (i == 0) ? 0 : (sInd[i] != sInd[i-1]);
      cv[u] = clc[b*SS + i];
      lsum += f[u];
    }
    int x = lsum;
    #pragma unroll
    for (int off = 1; off < 64; off <<= 1) {
      int v = __shfl_up(x, off, 64);
      if (lane >= off) x += v;
    }
    if (lane == 63) sWave[wid] = x;
    __syncthreads();
    int base = 0;
    for (int w2 = 0; w2 < wid; w2++) base += sWave[w2];
    int run = base + x - lsum;
    int rid[8];
    #pragma unroll
    for (int u = 0; u < 8; u++) {
      run += f[u];
      rid[u] = run;
      seg_id[b*SS + i0 + u] = run;
    }
    if (t == 255) nseg[b] = run + 1;

    #pragma unroll
    for (int u = 0; u < 8; u++) {
      if (cv[u] < 0) {
        atomicAdd(&sAC[rid[u]], 1);
        atomicMin(&sFA[rid[u]], i0 + u);
      }
    }
    __syncthreads();
    allowCnt[b*MAXSEG + t]   = sAC[t];
    firstAllow[b*MAXSEG + t] = sFA[t];

    int psum = 0;
    int p[8];
    #pragma unroll
    for (int u = 0; u < 8; u++) { p[u] = (cv[u] > 0) ? 1 : 0; psum += p[u]; }
    x = psum;
    #pragma unroll
    for (int off = 1; off < 64; off <<= 1) {
      int v = __shfl_up(x, off, 64);
      if (lane >= off) x += v;
    }
    __syncthreads();
    if (lane == 63) sWave[wid] = x;
    __syncthreads();
    base = 0;
    for (int w2 = 0; w2 < wid; w2++) base += sWave[w2];
    int rank = base + x - psum;
    #pragma unroll
    for (int u = 0; u < 8; u++) {
      if (p[u]) { pos_local[b*SS + rank] = i0 + u; rank++; }
    }
    if (t == 255) pos_cnt[b] = rank;
  }
}

// ---------------------------------------------------------------------------
// D2: U = tanh(segsum @ W^T + bias), f16 MFMA, direct-global fragments.
// Wave = independent 32x32 tile (2x2 of 16x16x32). 768 tiles -> 192 blocks.
// (unchanged from verified version)
// ---------------------------------------------------------------------------
__global__ __launch_bounds__(256) void k_gemmU(
    const _Float16* __restrict__ Ah, const _Float16* __restrict__ Wh,
    const float* __restrict__ bias, _Float16* __restrict__ Uh)
{
  int tid = threadIdx.x;
  int w = tid >> 6, lane = tid & 63;
  int tile = blockIdx.x*4 + w;          // 0..767 over 32 x 24 tiles
  int tm = tile / 24, tn = tile % 24;
  int rb = tm*32, cb = tn*32;
  int m0 = lane & 15, quad = lane >> 4;
  const _Float16* A0 = Ah + (size_t)(rb + m0)*HH + quad*8;
  const _Float16* A1 = A0 + (size_t)16*HH;
  const _Float16* B0 = Wh + (size_t)(cb + m0)*HH + quad*8;
  const _Float16* B1 = B0 + (size_t)16*HH;
  f32x4 acc00 = {0.f,0.f,0.f,0.f}, acc01 = {0.f,0.f,0.f,0.f};
  f32x4 acc10 = {0.f,0.f,0.f,0.f}, acc11 = {0.f,0.f,0.f,0.f};
  #pragma unroll 4
  for (int k0 = 0; k0 < HH; k0 += 32) {
    f16x8 a0 = *(const f16x8*)(A0 + k0);
    f16x8 a1 = *(const f16x8*)(A1 + k0);
    f16x8 b0 = *(const f16x8*)(B0 + k0);
    f16x8 b1 = *(const f16x8*)(B1 + k0);
    acc00 = __builtin_amdgcn_mfma_f32_16x16x32_f16(a0, b0, acc00, 0, 0, 0);
    acc01 = __builtin_amdgcn_mfma_f32_16x16x32_f16(a0, b1, acc01, 0, 0, 0);
    acc10 = __builtin_amdgcn_mfma_f32_16x16x32_f16(a1, b0, acc10, 0, 0, 0);
    acc11 = __builtin_amdgcn_mfma_f32_16x16x32_f16(a1, b1, acc11, 0, 0, 0);
  }
  float bc0 = bias[cb + m0], bc1 = bias[cb + 16 + m0];
  int r0 = rb + quad*4;
  #pragma unroll
  for (int i = 0; i < 4; i++) {
    Uh[(size_t)(r0+i)*HH    + cb + m0]      = (_Float16)tanhf(acc00[i] + bc0);
    Uh[(size_t)(r0+i)*HH    + cb + 16 + m0] = (_Float16)tanhf(acc01[i] + bc1);
    Uh[(size_t)(r0+16+i)*HH + cb + m0]      = (_Float16)tanhf(acc10[i] + bc0);
    Uh[(size_t)(r0+16+i)*HH + cb + 16 + m0] = (_Float16)tanhf(acc11[i] + bc1);
  }
}

// ---------------------------------------------------------------------------
// D3: fused Gram panel + row-LSE. Block = (b, 16-row panel), 1024 threads.
// 16 waves x 1 col-tile each — same 1024 MFMA waves / same FP order as the
// verified separate k_gram, but panel-complete per block so LSE runs from LDS.
// ---------------------------------------------------------------------------
__global__ __launch_bounds__(1024) void k_gramlse(
    const _Float16* __restrict__ Uh, const int* __restrict__ allowCnt,
    const int* __restrict__ firstAllow, const int* __restrict__ nseg,
    float* __restrict__ G, float* __restrict__ lse, int* __restrict__ amax)
{
  __shared__ float sG[16][257];          // +1 pad
  int t = threadIdx.x;
  int lane = t & 63, w = t >> 6;         // w = 0..15
  int blk = blockIdx.x;                  // 0..63
  int b = blk >> 4;
  int rb = (blk & 15) * 16;
  int m0 = lane & 15, quad = lane >> 4;
  const _Float16* Ub = Uh + (size_t)b*MAXSEG*HH;
  const _Float16* A0 = Ub + (size_t)(rb + m0)*HH + quad*8;
  int cb = w * 16;                       // this wave's col-tile
  const _Float16* B0 = Ub + (size_t)(cb + m0)*HH + quad*8;
  f32x4 acc = {0.f,0.f,0.f,0.f};
  #pragma unroll 4
  for (int k0 = 0; k0 < HH; k0 += 32) {
    f16x8 a  = *(const f16x8*)(A0 + k0);
    f16x8 bb = *(const f16x8*)(B0 + k0);
    acc = __builtin_amdgcn_mfma_f32_16x16x32_f16(a, bb, acc, 0, 0, 0);
  }
  float* Gb = G + (size_t)b*MAXSEG*MAXSEG;
  int r0 = quad*4;
  #pragma unroll
  for (int i = 0; i < 4; i++) {
    sG[r0 + i][cb + m0] = acc[i];
    Gb[(size_t)(rb + r0 + i)*MAXSEG + cb + m0] = acc[i];
  }
  __syncthreads();

  // ---- row LSE + argmax from LDS; wave w handles row rb+w ----
  int si = rb + w;
  if (si >= nseg[b]) return;
  const int* ac = allowCnt + b*MAXSEG;
  const int* fa = firstAllow + b*MAXSEG;
  float gv[4]; int av[4], fv[4];
  #pragma unroll
  for (int q = 0; q < 4; q++) {
    int s = lane + 64*q;
    gv[q] = sG[w][s]; av[q] = ac[s]; fv[q] = fa[s];
  }
  float m = -INFINITY;
  #pragma unroll
  for (int q = 0; q < 4; q++) if (av[q] > 0) m = fmaxf(m, gv[q]);
  #pragma unroll
  for (int off = 32; off > 0; off >>= 1) m = fmaxf(m, __shfl_xor(m, off, 64));
  float s = 0.f;
  #pragma unroll
  for (int q = 0; q < 4; q++) if (av[q] > 0) s += (float)av[q] * expf(gv[q] - m);
  #pragma unroll
  for (int off = 32; off > 0; off >>= 1) s += __shfl_xor(s, off, 64);
  float bv = -INFINITY; int bi = INT_MAX;
  #pragma unroll
  for (int q = 0; q < 4; q++) {
    if (av[q] > 0 && (gv[q] > bv || (gv[q] == bv && fv[q] < bi))) { bv = gv[q]; bi = fv[q]; }
  }
  #pragma unroll
  for (int off = 32; off > 0; off >>= 1) {
    float ov = __shfl_xor(bv, off, 64);
    int   oi = __shfl_xor(bi, off, 64);
    if (ov > bv || (ov == bv && oi < bi)) { bv = ov; bi = oi; }
  }
  if (lane == 0) {
    lse[b*MAXSEG + si]  = m + logf(s);
    amax[b*MAXSEG + si] = bi;
  }
}

// ---------------------------------------------------------------------------
// D4: single block — all positives; gather chain software-pipelined (stage
// all 8 items' loads level-by-level -> 4 latency waves instead of 32).
// Accumulation order per thread unchanged (ascending r).
// ---------------------------------------------------------------------------
__global__ __launch_bounds__(256) void k_posfinal(
    const float* __restrict__ G, const int* __restrict__ seg_id,
    const int* __restrict__ clc, const int* __restrict__ pos_local,
    const int* __restrict__ pos_cnt, const float* __restrict__ lse,
    const int* __restrict__ amax, float* __restrict__ out)
{
  __shared__ int sBase[BB+1];
  __shared__ float sL0[4], sC0[4], sL1[4], sC1[4];
  int t = threadIdx.x;
  if (t == 0) {
    int acc = 0; sBase[0] = 0;
    for (int b = 0; b < BB; b++) { acc += pos_cnt[b]; sBase[b+1] = acc; }
  }
  __syncthreads();
  int total = sBase[BB];
  if (total > NUM_POS) total = NUM_POS;

  int rs[8]; bool ok[8]; int bv[8];
  #pragma unroll
  for (int u = 0; u < 8; u++) {
    rs[u] = t + 256*u;
    ok[u] = rs[u] < total;
    int b = 0;
    if (ok[u]) { while (b < BB-1 && rs[u] >= sBase[b+1]) b++; }
    bv[u] = b;
  }
  int iv[8];
  #pragma unroll
  for (int u = 0; u < 8; u++)
    iv[u] = ok[u] ? pos_local[bv[u]*SS + (rs[u] - sBase[bv[u]])] : 0;
  int Lv[8], sv[8];
  #pragma unroll
  for (int u = 0; u < 8; u++) {
    Lv[u] = ok[u] ? clc[bv[u]*SS + iv[u]] : 0;
    sv[u] = ok[u] ? seg_id[bv[u]*SS + iv[u]] : 0;
  }
  int sLv[8], cLv[8];
  #pragma unroll
  for (int u = 0; u < 8; u++) {
    sLv[u] = ok[u] ? seg_id[bv[u]*SS + Lv[u]] : 0;
    cLv[u] = ok[u] ? clc[bv[u]*SS + Lv[u]] : 0;
  }
  float gv[8], lv[8]; int av[8];
  #pragma unroll
  for (int u = 0; u < 8; u++) {
    gv[u] = ok[u] ? G[((size_t)bv[u]*MAXSEG + sv[u])*MAXSEG + sLv[u]] : 0.f;
    lv[u] = ok[u] ? lse[bv[u]*MAXSEG + sv[u]] : 0.f;
    av[u] = ok[u] ? amax[bv[u]*MAXSEG + sv[u]] : -1;
  }

  float l0 = 0.f, c0 = 0.f, l1 = 0.f, c1 = 0.f;
  #pragma unroll
  for (int u = 0; u < 8; u++) {
    if (!ok[u]) continue;
    float vL = gv[u] + (cLv[u] < 0 ? 0.0f : NEG_BIG);
    float loss = lv[u] - vL;
    float corr = (av[u] == Lv[u]) ? 1.0f : 0.0f;
    if (rs[u] & 1) { l1 += loss; c1 += corr; } else { l0 += loss; c0 += corr; }
  }

  int lane = t & 63, wid = t >> 6;
  #pragma unroll
  for (int off = 32; off > 0; off >>= 1) {
    l0 += __shfl_down(l0, off, 64);
    c0 += __shfl_down(c0, off, 64);
    l1 += __shfl_down(l1, off, 64);
    c1 += __shfl_down(c1, off, 64);
  }
  if (lane == 0) { sL0[wid] = l0; sC0[wid] = c0; sL1[wid] = l1; sC1[wid] = c1; }
  __syncthreads();
  if (t == 0) {
    float L0 = sL0[0]+sL0[1]+sL0[2]+sL0[3];
    float C0 = sC0[0]+sC0[1]+sC0[2]+sC0[3];
    float L1 = sL1[0]+sL1[1]+sL1[2]+sL1[3];
    float C1 = sC1[0]+sC1[1]+sC1[2]+sC1[3];
    float n = (float)(NUM_POS/2);   // 1024
    out[0] = L0 / n;
    out[1] = C0;
    out[2] = n + 1e-6f;
    out[3] = L1 / n;
    out[4] = C1;
    out[5] = n + 1e-6f;
  }
}

// ---------------------------------------------------------------------------
extern "C" void kernel_launch(void* const* d_in, const int* in_sizes, int n_in,
                              void* d_out, int out_size, void* d_ws, size_t ws_size,
                              hipStream_t stream)
{
  const float* es   = (const float*)d_in[0];
  const float* W    = (const float*)d_in[1];
  const float* bias = (const float*)d_in[2];
  const int*   ind  = (const int*)d_in[3];
  const int*   clc  = (const int*)d_in[4];
  float* out = (float*)d_out;

  char* ws = (char*)d_ws;
  int*   nseg       = (int*)(ws + 0);
  int*   pos_cnt    = (int*)(ws + 256);
  int*   seg_id     = (int*)(ws + 8192);                 // B*S
  int*   pos_local  = (int*)(ws + 40960);                // B*S
  int*   allowCnt   = (int*)(ws + 73728);                // B*256
  int*   firstAllow = (int*)(ws + 77824);
  float* lse        = (float*)(ws + 81920);
  int*   amax       = (int*)(ws + 86016);
  _Float16* segsum_h = (_Float16*)(ws + 90112);          // 1024*768*2 = 1.5 MB
  _Float16* Wh       = (_Float16*)(ws + 1662976);        // 768*768*2 = 1.125 MB
  _Float16* Uh       = (_Float16*)(ws + 2842624);        // 1.5 MB
  float*    G        = (float*)(ws + 4415488);           // 1 MB

  k_stage1<<<BB*MAXSEG + BB + 576, 256, 0, stream>>>(
      es, W, ind, clc, Wh, segsum_h, seg_id, nseg,
      pos_local, pos_cnt, allowCnt, firstAllow);
  k_gemmU<<<192, 256, 0, stream>>>(segsum_h, Wh, bias, Uh);
  k_gramlse<<<BB*16, 1024, 0, stream>>>(Uh, allowCnt, firstAllow, nseg, G, lse, amax);
  k_posfinal<<<1, 256, 0, stream>>>(G, seg_id, clc, pos_local, pos_cnt, lse, amax, out);
}

// Round 4
// 121.108 us; speedup vs baseline: 3.2458x; 1.1022x over previous
//
#include <hip/hip_runtime.h>
#include <math.h>
#include <limits.h>

#define BB 4
#define SS 2048
#define HH 768
#define MAXSEG 256
#define NUM_POS (BB*(SS/4))   // 2048
#define NEG_BIG -1000000000.0f

typedef _Float16 f16x8 __attribute__((ext_vector_type(8)));
typedef _Float16 f16x4 __attribute__((ext_vector_type(4)));
typedef float    f32x4 __attribute__((ext_vector_type(4)));

// ---------------------------------------------------------------------------
// D1: blocks 0..3: per-batch scans. Blocks 4..579: W f32->f16 cast.
// (in-graph dispatches cost ~1us; boundaries are NOT the bottleneck --
//  rounds 1-3 established a fixed ~90us harness reset overhead inside the
//  timed window, so we optimize pure kernel time at full chip width)
// ---------------------------------------------------------------------------
__global__ __launch_bounds__(256) void k_scanW(
    const int* __restrict__ ind, const int* __restrict__ clc,
    const float* __restrict__ W, _Float16* __restrict__ Wh,
    int* __restrict__ seg_id, int* __restrict__ seg_start,
    int* __restrict__ nseg, int* __restrict__ pos_local, int* __restrict__ pos_cnt,
    int* __restrict__ allowCnt, int* __restrict__ firstAllow)
{
  int t = threadIdx.x;
  if (blockIdx.x >= BB) {
    int idx = (blockIdx.x - BB)*256 + t;     // float4 index; 147456 total
    float4 v = ((const float4*)W)[idx];
    f16x4 h;
    h[0] = (_Float16)v.x; h[1] = (_Float16)v.y;
    h[2] = (_Float16)v.z; h[3] = (_Float16)v.w;
    *(f16x4*)(Wh + (size_t)idx*4) = h;
    return;
  }
  int b = blockIdx.x;
  int lane = t & 63, wid = t >> 6;
  __shared__ int sInd[SS];
  __shared__ int sWave[4];
  __shared__ int sAC[MAXSEG];
  __shared__ int sFA[MAXSEG];
  for (int i = t; i < SS; i += 256) sInd[i] = ind[b*SS + i];
  sAC[t] = 0; sFA[t] = INT_MAX;
  __syncthreads();

  int i0 = t * 8;
  int f[8], cv[8];
  int lsum = 0;
  #pragma unroll
  for (int u = 0; u < 8; u++) {
    int i = i0 + u;
    f[u] = (i == 0) ? 0 : (sInd[i] != sInd[i-1]);
    cv[u] = clc[b*SS + i];
    lsum += f[u];
  }
  int x = lsum;
  #pragma unroll
  for (int off = 1; off < 64; off <<= 1) {
    int v = __shfl_up(x, off, 64);
    if (lane >= off) x += v;
  }
  if (lane == 63) sWave[wid] = x;
  __syncthreads();
  int base = 0;
  for (int w = 0; w < wid; w++) base += sWave[w];
  int run = base + x - lsum;
  int rid[8];
  #pragma unroll
  for (int u = 0; u < 8; u++) {
    int i = i0 + u;
    run += f[u];
    rid[u] = run;
    seg_id[b*SS + i] = run;
    if (f[u] || i == 0) seg_start[b*(MAXSEG+1) + run] = i;
  }
  if (t == 255) { nseg[b] = run + 1; seg_start[b*(MAXSEG+1) + run + 1] = SS; }

  #pragma unroll
  for (int u = 0; u < 8; u++) {
    if (cv[u] < 0) {
      atomicAdd(&sAC[rid[u]], 1);
      atomicMin(&sFA[rid[u]], i0 + u);
    }
  }
  __syncthreads();
  allowCnt[b*MAXSEG + t]   = sAC[t];
  firstAllow[b*MAXSEG + t] = sFA[t];

  int psum = 0;
  int p[8];
  #pragma unroll
  for (int u = 0; u < 8; u++) { p[u] = (cv[u] > 0) ? 1 : 0; psum += p[u]; }
  x = psum;
  #pragma unroll
  for (int off = 1; off < 64; off <<= 1) {
    int v = __shfl_up(x, off, 64);
    if (lane >= off) x += v;
  }
  __syncthreads();
  if (lane == 63) sWave[wid] = x;
  __syncthreads();
  base = 0;
  for (int w = 0; w < wid; w++) base += sWave[w];
  int rank = base + x - psum;
  #pragma unroll
  for (int u = 0; u < 8; u++) {
    if (p[u]) { pos_local[b*SS + rank] = i0 + u; rank++; }
  }
  if (t == 255) pos_cnt[b] = rank;
}

// ---------------------------------------------------------------------------
// D2: segment sums (f32 accumulate -> f16 out). 4-row unroll: 12 independent
// loads in flight cuts the longest-segment latency tail ~4x.
// ---------------------------------------------------------------------------
__global__ __launch_bounds__(256) void k_segsum(
    const float* __restrict__ es,
    const int* __restrict__ seg_start, const int* __restrict__ nseg,
    _Float16* __restrict__ segsum_h)
{
  int blk = blockIdx.x, t = threadIdx.x;
  int b = blk >> 8, s = blk & 255;
  _Float16* o = segsum_h + ((size_t)b*MAXSEG + s)*HH;
  if (s >= nseg[b]) {   // zero-fill missing segments (keep downstream NaN-free)
    o[t] = (_Float16)0.f; o[t+256] = (_Float16)0.f; o[t+512] = (_Float16)0.f;
    return;
  }
  int st = seg_start[b*(MAXSEG+1) + s];
  int en = seg_start[b*(MAXSEG+1) + s + 1];
  const float* base = es + (size_t)b*SS*HH;
  float a0 = 0.f, a1 = 0.f, a2 = 0.f;
  float b0 = 0.f, b1 = 0.f, b2 = 0.f;
  float c0 = 0.f, c1 = 0.f, c2 = 0.f;
  float d0 = 0.f, d1 = 0.f, d2 = 0.f;
  int i = st;
  for (; i + 4 <= en; i += 4) {
    const float* r0 = base + (size_t)i*HH;
    const float* r1 = r0 + HH;
    const float* r2 = r1 + HH;
    const float* r3 = r2 + HH;
    a0 += r0[t]; a1 += r0[t+256]; a2 += r0[t+512];
    b0 += r1[t]; b1 += r1[t+256]; b2 += r1[t+512];
    c0 += r2[t]; c1 += r2[t+256]; c2 += r2[t+512];
    d0 += r3[t]; d1 += r3[t+256]; d2 += r3[t+512];
  }
  for (; i < en; i++) {
    const float* r = base + (size_t)i*HH;
    a0 += r[t]; a1 += r[t+256]; a2 += r[t+512];
  }
  o[t]     = (_Float16)((a0 + b0) + (c0 + d0));
  o[t+256] = (_Float16)((a1 + b1) + (c1 + d1));
  o[t+512] = (_Float16)((a2 + b2) + (c2 + d2));
}

// ---------------------------------------------------------------------------
// D3: U = tanh(segsum @ W^T + bias), f16 MFMA, direct-global fragments.
// Wave = independent 32x32 tile (2x2 of 16x16x32). 768 tiles -> 192 blocks.
// ---------------------------------------------------------------------------
__global__ __launch_bounds__(256) void k_gemmU(
    const _Float16* __restrict__ Ah, const _Float16* __restrict__ Wh,
    const float* __restrict__ bias, _Float16* __restrict__ Uh)
{
  int tid = threadIdx.x;
  int w = tid >> 6, lane = tid & 63;
  int tile = blockIdx.x*4 + w;          // 0..767 over 32 x 24 tiles
  int tm = tile / 24, tn = tile % 24;
  int rb = tm*32, cb = tn*32;
  int m0 = lane & 15, quad = lane >> 4;
  const _Float16* A0 = Ah + (size_t)(rb + m0)*HH + quad*8;
  const _Float16* A1 = A0 + (size_t)16*HH;
  const _Float16* B0 = Wh + (size_t)(cb + m0)*HH + quad*8;
  const _Float16* B1 = B0 + (size_t)16*HH;
  f32x4 acc00 = {0.f,0.f,0.f,0.f}, acc01 = {0.f,0.f,0.f,0.f};
  f32x4 acc10 = {0.f,0.f,0.f,0.f}, acc11 = {0.f,0.f,0.f,0.f};
  #pragma unroll 4
  for (int k0 = 0; k0 < HH; k0 += 32) {
    f16x8 a0 = *(const f16x8*)(A0 + k0);
    f16x8 a1 = *(const f16x8*)(A1 + k0);
    f16x8 b0 = *(const f16x8*)(B0 + k0);
    f16x8 b1 = *(const f16x8*)(B1 + k0);
    acc00 = __builtin_amdgcn_mfma_f32_16x16x32_f16(a0, b0, acc00, 0, 0, 0);
    acc01 = __builtin_amdgcn_mfma_f32_16x16x32_f16(a0, b1, acc01, 0, 0, 0);
    acc10 = __builtin_amdgcn_mfma_f32_16x16x32_f16(a1, b0, acc10, 0, 0, 0);
    acc11 = __builtin_amdgcn_mfma_f32_16x16x32_f16(a1, b1, acc11, 0, 0, 0);
  }
  float bc0 = bias[cb + m0], bc1 = bias[cb + 16 + m0];
  int r0 = rb + quad*4;
  #pragma unroll
  for (int i = 0; i < 4; i++) {
    Uh[(size_t)(r0+i)*HH    + cb + m0]      = (_Float16)tanhf(acc00[i] + bc0);
    Uh[(size_t)(r0+i)*HH    + cb + 16 + m0] = (_Float16)tanhf(acc01[i] + bc1);
    Uh[(size_t)(r0+16+i)*HH + cb + m0]      = (_Float16)tanhf(acc10[i] + bc0);
    Uh[(size_t)(r0+16+i)*HH + cb + 16 + m0] = (_Float16)tanhf(acc11[i] + bc1);
  }
}

// ---------------------------------------------------------------------------
// D4: Gram G[b] = U[b] U[b]^T, f16 MFMA. Wave = one 16x16 tile.
// 1024 waves -> 256 blocks (full chip width; the fused 64-block variants of
// rounds 2/3 cost ~+8us by idling 3/4 of the CUs).
// ---------------------------------------------------------------------------
__global__ __launch_bounds__(256) void k_gram(
    const _Float16* __restrict__ Uh, float* __restrict__ G)
{
  int tid = threadIdx.x;
  int w = tid >> 6, lane = tid & 63;
  int tile = blockIdx.x*4 + w;          // 0..1023
  int b = tile >> 8, rem = tile & 255;
  int rb = (rem >> 4)*16, cb = (rem & 15)*16;
  int m0 = lane & 15, quad = lane >> 4;
  const _Float16* Ub = Uh + (size_t)b*MAXSEG*HH;
  const _Float16* A0 = Ub + (size_t)(rb + m0)*HH + quad*8;
  const _Float16* B0 = Ub + (size_t)(cb + m0)*HH + quad*8;
  f32x4 acc = {0.f,0.f,0.f,0.f};
  #pragma unroll 4
  for (int k0 = 0; k0 < HH; k0 += 32) {
    f16x8 a  = *(const f16x8*)(A0 + k0);
    f16x8 bb = *(const f16x8*)(B0 + k0);
    acc = __builtin_amdgcn_mfma_f32_16x16x32_f16(a, bb, acc, 0, 0, 0);
  }
  float* Gb = G + (size_t)b*MAXSEG*MAXSEG;
  int r0 = rb + quad*4;
  #pragma unroll
  for (int i = 0; i < 4; i++)
    Gb[(size_t)(r0+i)*MAXSEG + cb + m0] = acc[i];
}

// ---------------------------------------------------------------------------
// D5: per (b,seg) row: segment-level logsumexp + first-occurrence argmax.
// 256 blocks x 4 waves, wave = one row (full width).
// ---------------------------------------------------------------------------
__global__ __launch_bounds__(256) void k_seglse(
    const float* __restrict__ G, const int* __restrict__ allowCnt,
    const int* __restrict__ firstAllow, const int* __restrict__ nseg,
    float* __restrict__ lse, int* __restrict__ amax)
{
  int lane = threadIdx.x & 63, wid = threadIdx.x >> 6;
  int row = blockIdx.x * 4 + wid;
  int b = row >> 8, si = row & 255;
  if (si >= nseg[b]) return;
  const float* g = G + ((size_t)b*MAXSEG + si)*MAXSEG;
  const int* ac = allowCnt + b*MAXSEG;
  const int* fa = firstAllow + b*MAXSEG;

  float gv[4]; int av[4], fv[4];
  #pragma unroll
  for (int q = 0; q < 4; q++) {
    int s = lane + 64*q;
    gv[q] = g[s]; av[q] = ac[s]; fv[q] = fa[s];
  }
  float m = -INFINITY;
  #pragma unroll
  for (int q = 0; q < 4; q++) if (av[q] > 0) m = fmaxf(m, gv[q]);
  #pragma unroll
  for (int off = 32; off > 0; off >>= 1) m = fmaxf(m, __shfl_xor(m, off, 64));
  float s = 0.f;
  #pragma unroll
  for (int q = 0; q < 4; q++) if (av[q] > 0) s += (float)av[q] * expf(gv[q] - m);
  #pragma unroll
  for (int off = 32; off > 0; off >>= 1) s += __shfl_xor(s, off, 64);
  float bv = -INFINITY; int bi = INT_MAX;
  #pragma unroll
  for (int q = 0; q < 4; q++) {
    if (av[q] > 0 && (gv[q] > bv || (gv[q] == bv && fv[q] < bi))) { bv = gv[q]; bi = fv[q]; }
  }
  #pragma unroll
  for (int off = 32; off > 0; off >>= 1) {
    float ov = __shfl_xor(bv, off, 64);
    int   oi = __shfl_xor(bi, off, 64);
    if (ov > bv || (ov == bv && oi < bi)) { bv = ov; bi = oi; }
  }
  if (lane == 0) {
    lse[row]  = m + logf(s);
    amax[row] = bi;
  }
}

// ---------------------------------------------------------------------------
// D6: single block — all positives; gather chain software-pipelined (stage
// all 8 items' loads level-by-level -> 4 latency waves instead of ~32).
// Accumulation order per thread unchanged (ascending r).
// ---------------------------------------------------------------------------
__global__ __launch_bounds__(256) void k_posfinal(
    const float* __restrict__ G, const int* __restrict__ seg_id,
    const int* __restrict__ clc, const int* __restrict__ pos_local,
    const int* __restrict__ pos_cnt, const float* __restrict__ lse,
    const int* __restrict__ amax, float* __restrict__ out)
{
  __shared__ int sBase[BB+1];
  __shared__ float sL0[4], sC0[4], sL1[4], sC1[4];
  int t = threadIdx.x;
  if (t == 0) {
    int acc = 0; sBase[0] = 0;
    for (int b = 0; b < BB; b++) { acc += pos_cnt[b]; sBase[b+1] = acc; }
  }
  __syncthreads();
  int total = sBase[BB];
  if (total > NUM_POS) total = NUM_POS;

  int rs[8]; bool ok[8]; int bv[8];
  #pragma unroll
  for (int u = 0; u < 8; u++) {
    rs[u] = t + 256*u;
    ok[u] = rs[u] < total;
    int b = 0;
    if (ok[u]) { while (b < BB-1 && rs[u] >= sBase[b+1]) b++; }
    bv[u] = b;
  }
  int iv[8];
  #pragma unroll
  for (int u = 0; u < 8; u++)
    iv[u] = ok[u] ? pos_local[bv[u]*SS + (rs[u] - sBase[bv[u]])] : 0;
  int Lv[8], sv[8];
  #pragma unroll
  for (int u = 0; u < 8; u++) {
    Lv[u] = ok[u] ? clc[bv[u]*SS + iv[u]] : 0;
    sv[u] = ok[u] ? seg_id[bv[u]*SS + iv[u]] : 0;
  }
  int sLv[8], cLv[8];
  #pragma unroll
  for (int u = 0; u < 8; u++) {
    sLv[u] = ok[u] ? seg_id[bv[u]*SS + Lv[u]] : 0;
    cLv[u] = ok[u] ? clc[bv[u]*SS + Lv[u]] : 0;
  }
  float gv[8], lv[8]; int av[8];
  #pragma unroll
  for (int u = 0; u < 8; u++) {
    gv[u] = ok[u] ? G[((size_t)bv[u]*MAXSEG + sv[u])*MAXSEG + sLv[u]] : 0.f;
    lv[u] = ok[u] ? lse[bv[u]*MAXSEG + sv[u]] : 0.f;
    av[u] = ok[u] ? amax[bv[u]*MAXSEG + sv[u]] : -1;
  }

  float l0 = 0.f, c0 = 0.f, l1 = 0.f, c1 = 0.f;
  #pragma unroll
  for (int u = 0; u < 8; u++) {
    if (!ok[u]) continue;
    float vL = gv[u] + (cLv[u] < 0 ? 0.0f : NEG_BIG);
    float loss = lv[u] - vL;
    float corr = (av[u] == Lv[u]) ? 1.0f : 0.0f;
    if (rs[u] & 1) { l1 += loss; c1 += corr; } else { l0 += loss; c0 += corr; }
  }

  int lane = t & 63, wid = t >> 6;
  #pragma unroll
  for (int off = 32; off > 0; off >>= 1) {
    l0 += __shfl_down(l0, off, 64);
    c0 += __shfl_down(c0, off, 64);
    l1 += __shfl_down(l1, off, 64);
    c1 += __shfl_down(c1, off, 64);
  }
  if (lane == 0) { sL0[wid] = l0; sC0[wid] = c0; sL1[wid] = l1; sC1[wid] = c1; }
  __syncthreads();
  if (t == 0) {
    float L0 = sL0[0]+sL0[1]+sL0[2]+sL0[3];
    float C0 = sC0[0]+sC0[1]+sC0[2]+sC0[3];
    float L1 = sL1[0]+sL1[1]+sL1[2]+sL1[3];
    float C1 = sC1[0]+sC1[1]+sC1[2]+sC1[3];
    float n = (float)(NUM_POS/2);   // 1024
    out[0] = L0 / n;
    out[1] = C0;
    out[2] = n + 1e-6f;
    out[3] = L1 / n;
    out[4] = C1;
    out[5] = n + 1e-6f;
  }
}

// ---------------------------------------------------------------------------
extern "C" void kernel_launch(void* const* d_in, const int* in_sizes, int n_in,
                              void* d_out, int out_size, void* d_ws, size_t ws_size,
                              hipStream_t stream)
{
  const float* es   = (const float*)d_in[0];
  const float* W    = (const float*)d_in[1];
  const float* bias = (const float*)d_in[2];
  const int*   ind  = (const int*)d_in[3];
  const int*   clc  = (const int*)d_in[4];
  float* out = (float*)d_out;

  char* ws = (char*)d_ws;
  int*   nseg       = (int*)(ws + 0);
  int*   pos_cnt    = (int*)(ws + 256);
  int*   seg_start  = (int*)(ws + 1024);                 // B*(MAXSEG+1)
  int*   seg_id     = (int*)(ws + 8192);                 // B*S
  int*   pos_local  = (int*)(ws + 40960);                // B*S
  int*   allowCnt   = (int*)(ws + 73728);                // B*256
  int*   firstAllow = (int*)(ws + 77824);
  float* lse        = (float*)(ws + 81920);
  int*   amax       = (int*)(ws + 86016);
  _Float16* segsum_h = (_Float16*)(ws + 90112);          // 1024*768*2 = 1.5 MB
  _Float16* Wh       = (_Float16*)(ws + 1662976);        // 768*768*2 = 1.125 MB
  _Float16* Uh       = (_Float16*)(ws + 2842624);        // 1.5 MB
  float*    G        = (float*)(ws + 4415488);           // 1 MB

  k_scanW<<<BB + 576, 256, 0, stream>>>(ind, clc, W, Wh, seg_id, seg_start,
                                        nseg, pos_local, pos_cnt, allowCnt, firstAllow);
  k_segsum<<<BB*MAXSEG, 256, 0, stream>>>(es, seg_start, nseg, segsum_h);
  k_gemmU<<<192, 256, 0, stream>>>(segsum_h, Wh, bias, Uh);
  k_gram<<<256, 256, 0, stream>>>(Uh, G);
  k_seglse<<<(BB*MAXSEG)/4, 256, 0, stream>>>(G, allowCnt, firstAllow, nseg, lse, amax);
  k_posfinal<<<1, 256, 0, stream>>>(G, seg_id, clc, pos_local, pos_cnt, lse, amax, out);
}

// Round 5
// 117.371 us; speedup vs baseline: 3.3491x; 1.0318x over previous
//
#include <hip/hip_runtime.h>
#include <math.h>
#include <limits.h>

#define BB 4
#define SS 2048
#define HH 768
#define MAXSEG 256
#define NUM_POS (BB*(SS/4))   // 2048
#define NEG_BIG -1000000000.0f

typedef _Float16 f16x8 __attribute__((ext_vector_type(8)));
typedef _Float16 f16x4 __attribute__((ext_vector_type(4)));
typedef float    f32x4 __attribute__((ext_vector_type(4)));

// ---------------------------------------------------------------------------
// D1: blocks 0..3: per-batch scans. Blocks 4..579: W f32->f16 cast.
// ---------------------------------------------------------------------------
__global__ __launch_bounds__(256) void k_scanW(
    const int* __restrict__ ind, const int* __restrict__ clc,
    const float* __restrict__ W, _Float16* __restrict__ Wh,
    int* __restrict__ seg_id, int* __restrict__ seg_start,
    int* __restrict__ nseg, int* __restrict__ pos_local, int* __restrict__ pos_cnt,
    int* __restrict__ allowCnt, int* __restrict__ firstAllow)
{
  int t = threadIdx.x;
  if (blockIdx.x >= BB) {
    int idx = (blockIdx.x - BB)*256 + t;     // float4 index; 147456 total
    float4 v = ((const float4*)W)[idx];
    f16x4 h;
    h[0] = (_Float16)v.x; h[1] = (_Float16)v.y;
    h[2] = (_Float16)v.z; h[3] = (_Float16)v.w;
    *(f16x4*)(Wh + (size_t)idx*4) = h;
    return;
  }
  int b = blockIdx.x;
  int lane = t & 63, wid = t >> 6;
  __shared__ int sInd[SS];
  __shared__ int sWave[4];
  __shared__ int sAC[MAXSEG];
  __shared__ int sFA[MAXSEG];
  for (int i = t; i < SS; i += 256) sInd[i] = ind[b*SS + i];
  sAC[t] = 0; sFA[t] = INT_MAX;
  __syncthreads();

  int i0 = t * 8;
  int f[8], cv[8];
  int lsum = 0;
  #pragma unroll
  for (int u = 0; u < 8; u++) {
    int i = i0 + u;
    f[u] = (i == 0) ? 0 : (sInd[i] != sInd[i-1]);
    cv[u] = clc[b*SS + i];
    lsum += f[u];
  }
  int x = lsum;
  #pragma unroll
  for (int off = 1; off < 64; off <<= 1) {
    int v = __shfl_up(x, off, 64);
    if (lane >= off) x += v;
  }
  if (lane == 63) sWave[wid] = x;
  __syncthreads();
  int base = 0;
  for (int w = 0; w < wid; w++) base += sWave[w];
  int run = base + x - lsum;
  int rid[8];
  #pragma unroll
  for (int u = 0; u < 8; u++) {
    int i = i0 + u;
    run += f[u];
    rid[u] = run;
    seg_id[b*SS + i] = run;
    if (f[u] || i == 0) seg_start[b*(MAXSEG+1) + run] = i;
  }
  if (t == 255) { nseg[b] = run + 1; seg_start[b*(MAXSEG+1) + run + 1] = SS; }

  #pragma unroll
  for (int u = 0; u < 8; u++) {
    if (cv[u] < 0) {
      atomicAdd(&sAC[rid[u]], 1);
      atomicMin(&sFA[rid[u]], i0 + u);
    }
  }
  __syncthreads();
  allowCnt[b*MAXSEG + t]   = sAC[t];
  firstAllow[b*MAXSEG + t] = sFA[t];

  int psum = 0;
  int p[8];
  #pragma unroll
  for (int u = 0; u < 8; u++) { p[u] = (cv[u] > 0) ? 1 : 0; psum += p[u]; }
  x = psum;
  #pragma unroll
  for (int off = 1; off < 64; off <<= 1) {
    int v = __shfl_up(x, off, 64);
    if (lane >= off) x += v;
  }
  __syncthreads();
  if (lane == 63) sWave[wid] = x;
  __syncthreads();
  base = 0;
  for (int w = 0; w < wid; w++) base += sWave[w];
  int rank = base + x - psum;
  #pragma unroll
  for (int u = 0; u < 8; u++) {
    if (p[u]) { pos_local[b*SS + rank] = i0 + u; rank++; }
  }
  if (t == 255) pos_cnt[b] = rank;
}

// ---------------------------------------------------------------------------
// D2: segment sums. 1024 threads/block: 4 groups of 256 threads, each group
// sums a contiguous quarter of the segment's rows (4-row unrolled), then a
// deterministic 4-way LDS combine. Longest-segment serial chain /4 vs the
// 256-thread version.
// ---------------------------------------------------------------------------
__global__ __launch_bounds__(1024) void k_segsum(
    const float* __restrict__ es,
    const int* __restrict__ seg_start, const int* __restrict__ nseg,
    _Float16* __restrict__ segsum_h)
{
  __shared__ float sP[4][HH];            // 12 KB
  int blk = blockIdx.x, t = threadIdx.x;
  int b = blk >> 8, s = blk & 255;
  _Float16* o = segsum_h + ((size_t)b*MAXSEG + s)*HH;
  if (s >= nseg[b]) {   // zero-fill missing segments (keep downstream NaN-free)
    if (t < HH) o[t] = (_Float16)0.f;
    return;
  }
  int g = t >> 8, tt = t & 255;          // group 0..3, col-thread 0..255
  int st = seg_start[b*(MAXSEG+1) + s];
  int en = seg_start[b*(MAXSEG+1) + s + 1];
  int len = en - st;
  int q = (len + 3) >> 2;                // rows per group (last may be short)
  int gs = st + g*q;
  int ge = gs + q; if (ge > en) ge = en;
  const float* base = es + (size_t)b*SS*HH;
  float a0 = 0.f, a1 = 0.f, a2 = 0.f;
  float b0 = 0.f, b1 = 0.f, b2 = 0.f;
  float c0 = 0.f, c1 = 0.f, c2 = 0.f;
  float d0 = 0.f, d1 = 0.f, d2 = 0.f;
  int i = gs;
  for (; i + 4 <= ge; i += 4) {
    const float* r0 = base + (size_t)i*HH;
    const float* r1 = r0 + HH;
    const float* r2 = r1 + HH;
    const float* r3 = r2 + HH;
    a0 += r0[tt]; a1 += r0[tt+256]; a2 += r0[tt+512];
    b0 += r1[tt]; b1 += r1[tt+256]; b2 += r1[tt+512];
    c0 += r2[tt]; c1 += r2[tt+256]; c2 += r2[tt+512];
    d0 += r3[tt]; d1 += r3[tt+256]; d2 += r3[tt+512];
  }
  for (; i < ge; i++) {
    const float* r = base + (size_t)i*HH;
    a0 += r[tt]; a1 += r[tt+256]; a2 += r[tt+512];
  }
  sP[g][tt]     = (a0 + b0) + (c0 + d0);
  sP[g][tt+256] = (a1 + b1) + (c1 + d1);
  sP[g][tt+512] = (a2 + b2) + (c2 + d2);
  __syncthreads();
  if (t < HH) {
    float v = (sP[0][t] + sP[1][t]) + (sP[2][t] + sP[3][t]);
    o[t] = (_Float16)v;
  }
}

// ---------------------------------------------------------------------------
// D3: U = tanh(segsum @ W^T + bias), f16 MFMA, direct-global fragments.
// 256 blocks x 3 waves (192 thr) = 768 tiles -> all 256 CUs active
// (192-block/4-wave layout left 64 CUs idle on a latency-bound loop).
// ---------------------------------------------------------------------------
__global__ __launch_bounds__(192) void k_gemmU(
    const _Float16* __restrict__ Ah, const _Float16* __restrict__ Wh,
    const float* __restrict__ bias, _Float16* __restrict__ Uh)
{
  int tid = threadIdx.x;
  int w = tid >> 6, lane = tid & 63;
  int tile = blockIdx.x*3 + w;          // 0..767 over 32 x 24 tiles
  int tm = tile / 24, tn = tile % 24;
  int rb = tm*32, cb = tn*32;
  int m0 = lane & 15, quad = lane >> 4;
  const _Float16* A0 = Ah + (size_t)(rb + m0)*HH + quad*8;
  const _Float16* A1 = A0 + (size_t)16*HH;
  const _Float16* B0 = Wh + (size_t)(cb + m0)*HH + quad*8;
  const _Float16* B1 = B0 + (size_t)16*HH;
  f32x4 acc00 = {0.f,0.f,0.f,0.f}, acc01 = {0.f,0.f,0.f,0.f};
  f32x4 acc10 = {0.f,0.f,0.f,0.f}, acc11 = {0.f,0.f,0.f,0.f};
  #pragma unroll 4
  for (int k0 = 0; k0 < HH; k0 += 32) {
    f16x8 a0 = *(const f16x8*)(A0 + k0);
    f16x8 a1 = *(const f16x8*)(A1 + k0);
    f16x8 b0 = *(const f16x8*)(B0 + k0);
    f16x8 b1 = *(const f16x8*)(B1 + k0);
    acc00 = __builtin_amdgcn_mfma_f32_16x16x32_f16(a0, b0, acc00, 0, 0, 0);
    acc01 = __builtin_amdgcn_mfma_f32_16x16x32_f16(a0, b1, acc01, 0, 0, 0);
    acc10 = __builtin_amdgcn_mfma_f32_16x16x32_f16(a1, b0, acc10, 0, 0, 0);
    acc11 = __builtin_amdgcn_mfma_f32_16x16x32_f16(a1, b1, acc11, 0, 0, 0);
  }
  float bc0 = bias[cb + m0], bc1 = bias[cb + 16 + m0];
  int r0 = rb + quad*4;
  #pragma unroll
  for (int i = 0; i < 4; i++) {
    Uh[(size_t)(r0+i)*HH    + cb + m0]      = (_Float16)tanhf(acc00[i] + bc0);
    Uh[(size_t)(r0+i)*HH    + cb + 16 + m0] = (_Float16)tanhf(acc01[i] + bc1);
    Uh[(size_t)(r0+16+i)*HH + cb + m0]      = (_Float16)tanhf(acc10[i] + bc0);
    Uh[(size_t)(r0+16+i)*HH + cb + 16 + m0] = (_Float16)tanhf(acc11[i] + bc1);
  }
}

// ---------------------------------------------------------------------------
// D4: Gram G[b] = U[b] U[b]^T, f16 MFMA. Wave = one 16x16 tile.
// 1024 waves -> 256 blocks (full chip width).
// ---------------------------------------------------------------------------
__global__ __launch_bounds__(256) void k_gram(
    const _Float16* __restrict__ Uh, float* __restrict__ G)
{
  int tid = threadIdx.x;
  int w = tid >> 6, lane = tid & 63;
  int tile = blockIdx.x*4 + w;          // 0..1023
  int b = tile >> 8, rem = tile & 255;
  int rb = (rem >> 4)*16, cb = (rem & 15)*16;
  int m0 = lane & 15, quad = lane >> 4;
  const _Float16* Ub = Uh + (size_t)b*MAXSEG*HH;
  const _Float16* A0 = Ub + (size_t)(rb + m0)*HH + quad*8;
  const _Float16* B0 = Ub + (size_t)(cb + m0)*HH + quad*8;
  f32x4 acc = {0.f,0.f,0.f,0.f};
  #pragma unroll 4
  for (int k0 = 0; k0 < HH; k0 += 32) {
    f16x8 a  = *(const f16x8*)(A0 + k0);
    f16x8 bb = *(const f16x8*)(B0 + k0);
    acc = __builtin_amdgcn_mfma_f32_16x16x32_f16(a, bb, acc, 0, 0, 0);
  }
  float* Gb = G + (size_t)b*MAXSEG*MAXSEG;
  int r0 = rb + quad*4;
  #pragma unroll
  for (int i = 0; i < 4; i++)
    Gb[(size_t)(r0+i)*MAXSEG + cb + m0] = acc[i];
}

// ---------------------------------------------------------------------------
// D5: per (b,seg) row: masked logsumexp + first-occurrence argmax.
// Vectorized float4/int4 loads (lane covers cols lane*4..lane*4+3).
// ---------------------------------------------------------------------------
__global__ __launch_bounds__(256) void k_seglse(
    const float* __restrict__ G, const int* __restrict__ allowCnt,
    const int* __restrict__ firstAllow, const int* __restrict__ nseg,
    float* __restrict__ lse, int* __restrict__ amax)
{
  int lane = threadIdx.x & 63, wid = threadIdx.x >> 6;
  int row = blockIdx.x * 4 + wid;
  int b = row >> 8, si = row & 255;
  if (si >= nseg[b]) return;
  const float* g = G + ((size_t)b*MAXSEG + si)*MAXSEG;
  const int* ac = allowCnt + b*MAXSEG;
  const int* fa = firstAllow + b*MAXSEG;

  float4 gv = ((const float4*)g)[lane];
  int4   av = ((const int4*)ac)[lane];
  int4   fv = ((const int4*)fa)[lane];
  float gvv[4] = {gv.x, gv.y, gv.z, gv.w};
  int   avv[4] = {av.x, av.y, av.z, av.w};
  int   fvv[4] = {fv.x, fv.y, fv.z, fv.w};

  float m = -INFINITY;
  #pragma unroll
  for (int q = 0; q < 4; q++) if (avv[q] > 0) m = fmaxf(m, gvv[q]);
  #pragma unroll
  for (int off = 32; off > 0; off >>= 1) m = fmaxf(m, __shfl_xor(m, off, 64));
  float s = 0.f;
  #pragma unroll
  for (int q = 0; q < 4; q++) if (avv[q] > 0) s += (float)avv[q] * expf(gvv[q] - m);
  #pragma unroll
  for (int off = 32; off > 0; off >>= 1) s += __shfl_xor(s, off, 64);
  float bv = -INFINITY; int bi = INT_MAX;
  #pragma unroll
  for (int q = 0; q < 4; q++) {
    if (avv[q] > 0 && (gvv[q] > bv || (gvv[q] == bv && fvv[q] < bi))) { bv = gvv[q]; bi = fvv[q]; }
  }
  #pragma unroll
  for (int off = 32; off > 0; off >>= 1) {
    float ov = __shfl_xor(bv, off, 64);
    int   oi = __shfl_xor(bi, off, 64);
    if (ov > bv || (ov == bv && oi < bi)) { bv = ov; bi = oi; }
  }
  if (lane == 0) {
    lse[row]  = m + logf(s);
    amax[row] = bi;
  }
}

// ---------------------------------------------------------------------------
// D6: single block — all positives; gather chain software-pipelined (stage
// all 8 items' loads level-by-level -> 4 latency waves instead of ~32).
// ---------------------------------------------------------------------------
__global__ __launch_bounds__(256) void k_posfinal(
    const float* __restrict__ G, const int* __restrict__ seg_id,
    const int* __restrict__ clc, const int* __restrict__ pos_local,
    const int* __restrict__ pos_cnt, const float* __restrict__ lse,
    const int* __restrict__ amax, float* __restrict__ out)
{
  __shared__ int sBase[BB+1];
  __shared__ float sL0[4], sC0[4], sL1[4], sC1[4];
  int t = threadIdx.x;
  if (t == 0) {
    int acc = 0; sBase[0] = 0;
    for (int b = 0; b < BB; b++) { acc += pos_cnt[b]; sBase[b+1] = acc; }
  }
  __syncthreads();
  int total = sBase[BB];
  if (total > NUM_POS) total = NUM_POS;

  int rs[8]; bool ok[8]; int bv[8];
  #pragma unroll
  for (int u = 0; u < 8; u++) {
    rs[u] = t + 256*u;
    ok[u] = rs[u] < total;
    int b = 0;
    if (ok[u]) { while (b < BB-1 && rs[u] >= sBase[b+1]) b++; }
    bv[u] = b;
  }
  int iv[8];
  #pragma unroll
  for (int u = 0; u < 8; u++)
    iv[u] = ok[u] ? pos_local[bv[u]*SS + (rs[u] - sBase[bv[u]])] : 0;
  int Lv[8], sv[8];
  #pragma unroll
  for (int u = 0; u < 8; u++) {
    Lv[u] = ok[u] ? clc[bv[u]*SS + iv[u]] : 0;
    sv[u] = ok[u] ? seg_id[bv[u]*SS + iv[u]] : 0;
  }
  int sLv[8], cLv[8];
  #pragma unroll
  for (int u = 0; u < 8; u++) {
    sLv[u] = ok[u] ? seg_id[bv[u]*SS + Lv[u]] : 0;
    cLv[u] = ok[u] ? clc[bv[u]*SS + Lv[u]] : 0;
  }
  float gv[8], lv[8]; int av[8];
  #pragma unroll
  for (int u = 0; u < 8; u++) {
    gv[u] = ok[u] ? G[((size_t)bv[u]*MAXSEG + sv[u])*MAXSEG + sLv[u]] : 0.f;
    lv[u] = ok[u] ? lse[bv[u]*MAXSEG + sv[u]] : 0.f;
    av[u] = ok[u] ? amax[bv[u]*MAXSEG + sv[u]] : -1;
  }

  float l0 = 0.f, c0 = 0.f, l1 = 0.f, c1 = 0.f;
  #pragma unroll
  for (int u = 0; u < 8; u++) {
    if (!ok[u]) continue;
    float vL = gv[u] + (cLv[u] < 0 ? 0.0f : NEG_BIG);
    float loss = lv[u] - vL;
    float corr = (av[u] == Lv[u]) ? 1.0f : 0.0f;
    if (rs[u] & 1) { l1 += loss; c1 += corr; } else { l0 += loss; c0 += corr; }
  }

  int lane = t & 63, wid = t >> 6;
  #pragma unroll
  for (int off = 32; off > 0; off >>= 1) {
    l0 += __shfl_down(l0, off, 64);
    c0 += __shfl_down(c0, off, 64);
    l1 += __shfl_down(l1, off, 64);
    c1 += __shfl_down(c1, off, 64);
  }
  if (lane == 0) { sL0[wid] = l0; sC0[wid] = c0; sL1[wid] = l1; sC1[wid] = c1; }
  __syncthreads();
  if (t == 0) {
    float L0 = sL0[0]+sL0[1]+sL0[2]+sL0[3];
    float C0 = sC0[0]+sC0[1]+sC0[2]+sC0[3];
    float L1 = sL1[0]+sL1[1]+sL1[2]+sL1[3];
    float C1 = sC1[0]+sC1[1]+sC1[2]+sC1[3];
    float n = (float)(NUM_POS/2);   // 1024
    out[0] = L0 / n;
    out[1] = C0;
    out[2] = n + 1e-6f;
    out[3] = L1 / n;
    out[4] = C1;
    out[5] = n + 1e-6f;
  }
}

// ---------------------------------------------------------------------------
extern "C" void kernel_launch(void* const* d_in, const int* in_sizes, int n_in,
                              void* d_out, int out_size, void* d_ws, size_t ws_size,
                              hipStream_t stream)
{
  const float* es   = (const float*)d_in[0];
  const float* W    = (const float*)d_in[1];
  const float* bias = (const float*)d_in[2];
  const int*   ind  = (const int*)d_in[3];
  const int*   clc  = (const int*)d_in[4];
  float* out = (float*)d_out;

  char* ws = (char*)d_ws;
  int*   nseg       = (int*)(ws + 0);
  int*   pos_cnt    = (int*)(ws + 256);
  int*   seg_start  = (int*)(ws + 1024);                 // B*(MAXSEG+1)
  int*   seg_id     = (int*)(ws + 8192);                 // B*S
  int*   pos_local  = (int*)(ws + 40960);                // B*S
  int*   allowCnt   = (int*)(ws + 73728);                // B*256
  int*   firstAllow = (int*)(ws + 77824);
  float* lse        = (float*)(ws + 81920);
  int*   amax       = (int*)(ws + 86016);
  _Float16* segsum_h = (_Float16*)(ws + 90112);          // 1024*768*2 = 1.5 MB
  _Float16* Wh       = (_Float16*)(ws + 1662976);        // 768*768*2 = 1.125 MB
  _Float16* Uh       = (_Float16*)(ws + 2842624);        // 1.5 MB
  float*    G        = (float*)(ws + 4415488);           // 1 MB

  k_scanW<<<BB + 576, 256, 0, stream>>>(ind, clc, W, Wh, seg_id, seg_start,
                                        nseg, pos_local, pos_cnt, allowCnt, firstAllow);
  k_segsum<<<BB*MAXSEG, 1024, 0, stream>>>(es, seg_start, nseg, segsum_h);
  k_gemmU<<<256, 192, 0, stream>>>(segsum_h, Wh, bias, Uh);
  k_gram<<<256, 256, 0, stream>>>(Uh, G);
  k_seglse<<<(BB*MAXSEG)/4, 256, 0, stream>>>(G, allowCnt, firstAllow, nseg, lse, amax);
  k_posfinal<<<1, 256, 0, stream>>>(G, seg_id, clc, pos_local, pos_cnt, lse, amax, out);
}